// Round 5
// baseline (556.569 us; speedup 1.0000x reference)
//
#include <hip/hip_runtime.h>
#include <hip/hip_bf16.h>

#define NB 32
#define NT 1024
#define ND 512
#define NS 1024

#define CTX_ELEMS (32u * 1024u * 512u)          // 16777216
#define SP_SCRATCH_OFF (CTX_ELEMS - 32u*1024u)  // fallback sp stash in contexts tail

__device__ __forceinline__ float vlog2(float x) {
    float r; asm("v_log_f32 %0, %1" : "=v"(r) : "v"(x)); return r;
}
__device__ __forceinline__ float vexp2(float x) {
    float r; asm("v_exp_f32 %0, %1" : "=v"(r) : "v"(x)); return r;
}
__device__ __forceinline__ float vrcp(float x) {
    float r; asm("v_rcp_f32 %0, %1" : "=v"(r) : "v"(x)); return r;
}

template<int ctrl, int rm, int bm, bool bc>
__device__ __forceinline__ float dppadd(float x) {
    int y = __builtin_amdgcn_update_dpp(0, __float_as_int(x), ctrl, rm, bm, bc);
    return x + __int_as_float(y);
}
// full-wave sum; valid result lands in lane 63
__device__ __forceinline__ float reduce63(float x) {
    x = dppadd<0x111, 0xf, 0xf, true >(x);   // row_shr:1
    x = dppadd<0x112, 0xf, 0xf, true >(x);   // row_shr:2
    x = dppadd<0x114, 0xf, 0xf, true >(x);   // row_shr:4
    x = dppadd<0x118, 0xf, 0xf, true >(x);   // row_shr:8
    x = dppadd<0x142, 0xa, 0xf, false>(x);   // row_bcast:15
    x = dppadd<0x143, 0xc, 0xf, false>(x);   // row_bcast:31
    return x;
}
// lane L receives x from lane L-1 (lane 0 gets 0)
__device__ __forceinline__ float wave_shr1(float x) {
    int y = __builtin_amdgcn_update_dpp(0, __float_as_int(x), 0x138, 0xf, 0xf, true);
    return __int_as_float(y);
}

__device__ __forceinline__ void lds_barrier() {
    asm volatile("s_waitcnt lgkmcnt(0)" ::: "memory");
    __builtin_amdgcn_s_barrier();
    asm volatile("" ::: "memory");
}

// ---------------- kernel 1: sp[b][t] = sigmoid(dot(x[b,t,:], W) + bias) ----------------
__global__ __launch_bounds__(256) void sp_kernel(const float* __restrict__ x,
                                                 const float* __restrict__ W,
                                                 const float* __restrict__ bias,
                                                 float* __restrict__ sp)
{
    const int lane = threadIdx.x & 63;
    const int wid  = threadIdx.x >> 6;
    const int row  = blockIdx.x * 4 + wid;          // b*NT + t
    const float4* xr = reinterpret_cast<const float4*>(x + (size_t)row * ND) + lane * 2;
    const float4* wr = reinterpret_cast<const float4*>(W) + lane * 2;
    float4 xa = xr[0], xb = xr[1];
    float4 wa = wr[0], wb = wr[1];
    float d = xa.x*wa.x + xa.y*wa.y + xa.z*wa.z + xa.w*wa.w
            + xb.x*wb.x + xb.y*wb.y + xb.z*wb.z + xb.w*wb.w;
    #pragma unroll
    for (int m = 1; m < 64; m <<= 1) d += __shfl_xor(d, m);
    if (lane == 0) {
        float z = d + bias[0];
        float e = vexp2(-z * 1.442695040888963f);
        sp[row] = 1.0f / (1.0f + e);
    }
}

// ---------------- kernel 2: fused scan + GEMM with progress flags ----------------
// grid: blocks 0..31 = scan (one per batch row), blocks 32..287 = GEMM tiles.
// GEMM tile decode (g = bid-32): sb = g>>6 (s-block, sb-major so earliest-ready
// tiles are dispatched first), b = (g&63)>>1, nb = g&1.
typedef __bf16 bf16x8 __attribute__((ext_vector_type(8)));
typedef float  f32x4  __attribute__((ext_vector_type(4)));

#define BM 256
#define BN 256
#define BK 32
#define LDP 40   // padded leading dim (bf16 elems)

__global__ __launch_bounds__(512, 2) void fused_kernel(const float* __restrict__ sp,
                                                       const float* __restrict__ x,
                                                       float* __restrict__ alphas,
                                                       float* __restrict__ contexts,
                                                       int* __restrict__ flags)
{
    __shared__ __align__(16) __bf16 As[BM * LDP];   // 20 KB (gemm)
    __shared__ __align__(16) __bf16 Xs[BN * LDP];   // 20 KB (gemm)
    __shared__ float r1[2][4];                       // scan exchange
    __shared__ float r2[2][4];
    __shared__ float rb[2][4];

    const int bid = blockIdx.x;
    const int tx  = threadIdx.x;

    if (bid < NB) {
        // ================= scan path (R2-proven structure, waves 0-3 active) ========
        const int b = bid;
        if (tx >= 256) {
            // barrier-count-matching dummy waves
            __syncthreads();
            for (int s = 0; s < NS; ++s) {
                __syncthreads();
                if ((s & 255) == 255) __syncthreads();
            }
            return;
        }
        const int lane = tx & 63;
        const int wid  = tx >> 6;

        float spv[4], raw[4];
        {
            float4 v = *reinterpret_cast<const float4*>(sp + (size_t)b * NT + tx * 4);
            spv[0] = v.x; spv[1] = v.y; spv[2] = v.z; spv[3] = v.w;
        }
        #pragma unroll
        for (int j = 0; j < 4; ++j) raw[j] = 1e-7f;
        if (tx == 0) raw[0] = 1.0f;
        float carry = (wid == 0) ? 0.0f : 1e-7f;

        {
            float p2 = fmaf(raw[0], spv[0], fmaf(raw[1], spv[1], fmaf(raw[2], spv[2], raw[3]*spv[3])));
            p2 = reduce63(p2);
            if (lane == 63) r2[1][wid] = p2;
        }
        __syncthreads();
        float u;
        {
            float4 v2 = *reinterpret_cast<const float4*>(r2[1]);
            u = (v2.x + v2.y) + (v2.z + v2.w);
        }
        float inv = 1.0f;

        float* outp = alphas + (size_t)b * NS * NT + tx * 4;

        for (int s = 0; s < NS; ++s) {
            const int p = s & 1;
            const float sq = 1.7f - fabsf(u - 0.5f);
            const float c1 = (1.0f - u) * inv;
            const float c0 = u * inv;

            float prev = wave_shr1(raw[3]);
            float sh0  = (lane == 0) ? carry : prev;

            float anew[4];
            {
                float v0 = fmaf(c1, raw[0], fmaf(c0, sh0,    1e-6f));
                float v1 = fmaf(c1, raw[1], fmaf(c0, raw[0], 1e-6f));
                float v2 = fmaf(c1, raw[2], fmaf(c0, raw[1], 1e-6f));
                float v3 = fmaf(c1, raw[3], fmaf(c0, raw[2], 1e-6f));
                anew[0] = vexp2(sq * vlog2(v0));
                anew[1] = vexp2(sq * vlog2(v1));
                anew[2] = vexp2(sq * vlog2(v2));
                anew[3] = vexp2(sq * vlog2(v3));
            }

            float p1 = (anew[0] + anew[1]) + (anew[2] + anew[3]);
            float p2 = fmaf(anew[0], spv[0], anew[1]*spv[1]) + fmaf(anew[2], spv[2], anew[3]*spv[3]);
            p1 = reduce63(p1);
            p2 = reduce63(p2);
            if (lane == 63) { r1[p][wid] = p1; r2[p][wid] = p2; rb[p][wid] = anew[3]; }
            __syncthreads();

            float4 v1 = *reinterpret_cast<const float4*>(r1[p]);
            float4 v2 = *reinterpret_cast<const float4*>(r2[p]);
            float bc  = rb[p][(wid == 0) ? 0 : (wid - 1)];
            carry = (wid == 0) ? 0.0f : bc;

            float t1 = (v1.x + v1.y) + (v1.z + v1.w);
            float t2 = (v2.x + v2.y) + (v2.z + v2.w);
            inv = vrcp(t1);
            u   = t2 * inv;

            float4 o;
            o.x = anew[0] * inv; o.y = anew[1] * inv; o.z = anew[2] * inv; o.w = anew[3] * inv;
            *reinterpret_cast<float4*>(outp + (size_t)s * NT) = o;

            #pragma unroll
            for (int j = 0; j < 4; ++j) raw[j] = anew[j];

            // publish progress every 256 steps
            if ((s & 255) == 255) {
                asm volatile("s_waitcnt vmcnt(0)" ::: "memory");   // drain this wave's alphas stores
                __syncthreads();                                    // all waves drained
                if (tx == 0)
                    __hip_atomic_store(&flags[b], (s >> 8) + 1,
                                       __ATOMIC_RELEASE, __HIP_MEMORY_SCOPE_AGENT);
            }
        }
        return;
    }

    // ================= GEMM path =================
    const int g  = bid - NB;
    const int sb = g >> 6;            // 0..3
    const int b  = (g & 63) >> 1;     // 0..31
    const int nb = g & 1;             // 0..1
    const int s0 = sb * BM;
    const int n0 = nb * BN;

    // wait until this s-block's alphas rows are published
    while (__hip_atomic_load(&flags[b], __ATOMIC_ACQUIRE, __HIP_MEMORY_SCOPE_AGENT) < sb + 1)
        __builtin_amdgcn_s_sleep(2);

    const int lane = tx & 63;
    const int wid  = tx >> 6;
    const int wm = wid >> 2;          // 0..1  (128-row slab)
    const int wn = wid & 3;           // 0..3  (64-col slab)
    const int lr = lane & 15;
    const int lk = (lane >> 4) * 8;

    f32x4 acc[8][4];
    #pragma unroll
    for (int i = 0; i < 8; ++i)
        #pragma unroll
        for (int j = 0; j < 4; ++j) acc[i][j] = (f32x4){0.f, 0.f, 0.f, 0.f};

    const int arow = tx >> 1;
    const int akb  = (tx & 1) * 16;
    const int xk0 = tx >> 6;          // 0..7
    const int xn4 = (tx & 63) * 4;    // 0..252

    const float* ap = alphas + ((size_t)b * NS + s0 + arow) * NT + akb;
    const float* xp = x + ((size_t)b * NT + xk0) * ND + n0 + xn4;

    float4 va0 = reinterpret_cast<const float4*>(ap)[0];
    float4 va1 = reinterpret_cast<const float4*>(ap)[1];
    float4 va2 = reinterpret_cast<const float4*>(ap)[2];
    float4 va3 = reinterpret_cast<const float4*>(ap)[3];
    float4 vx0 = *reinterpret_cast<const float4*>(xp + 0 * 8 * ND);
    float4 vx1 = *reinterpret_cast<const float4*>(xp + 1 * 8 * ND);
    float4 vx2 = *reinterpret_cast<const float4*>(xp + 2 * 8 * ND);
    float4 vx3 = *reinterpret_cast<const float4*>(xp + 3 * 8 * ND);
    ap += BK;
    xp += (size_t)BK * ND;

    for (int k0 = 0; k0 < NT; k0 += BK) {
        {
            bf16x8 w0, w1;
            w0[0]=(__bf16)va0.x; w0[1]=(__bf16)va0.y; w0[2]=(__bf16)va0.z; w0[3]=(__bf16)va0.w;
            w0[4]=(__bf16)va1.x; w0[5]=(__bf16)va1.y; w0[6]=(__bf16)va1.z; w0[7]=(__bf16)va1.w;
            w1[0]=(__bf16)va2.x; w1[1]=(__bf16)va2.y; w1[2]=(__bf16)va2.z; w1[3]=(__bf16)va2.w;
            w1[4]=(__bf16)va3.x; w1[5]=(__bf16)va3.y; w1[6]=(__bf16)va3.z; w1[7]=(__bf16)va3.w;
            *reinterpret_cast<bf16x8*>(&As[arow * LDP + akb])     = w0;
            *reinterpret_cast<bf16x8*>(&As[arow * LDP + akb + 8]) = w1;
            const int xk = xk0;
            Xs[(xn4+0)*LDP + xk]      = (__bf16)vx0.x;
            Xs[(xn4+1)*LDP + xk]      = (__bf16)vx0.y;
            Xs[(xn4+2)*LDP + xk]      = (__bf16)vx0.z;
            Xs[(xn4+3)*LDP + xk]      = (__bf16)vx0.w;
            Xs[(xn4+0)*LDP + xk + 8]  = (__bf16)vx1.x;
            Xs[(xn4+1)*LDP + xk + 8]  = (__bf16)vx1.y;
            Xs[(xn4+2)*LDP + xk + 8]  = (__bf16)vx1.z;
            Xs[(xn4+3)*LDP + xk + 8]  = (__bf16)vx1.w;
            Xs[(xn4+0)*LDP + xk + 16] = (__bf16)vx2.x;
            Xs[(xn4+1)*LDP + xk + 16] = (__bf16)vx2.y;
            Xs[(xn4+2)*LDP + xk + 16] = (__bf16)vx2.z;
            Xs[(xn4+3)*LDP + xk + 16] = (__bf16)vx2.w;
            Xs[(xn4+0)*LDP + xk + 24] = (__bf16)vx3.x;
            Xs[(xn4+1)*LDP + xk + 24] = (__bf16)vx3.y;
            Xs[(xn4+2)*LDP + xk + 24] = (__bf16)vx3.z;
            Xs[(xn4+3)*LDP + xk + 24] = (__bf16)vx3.w;
        }
        if (k0 + BK < NT) {
            va0 = reinterpret_cast<const float4*>(ap)[0];
            va1 = reinterpret_cast<const float4*>(ap)[1];
            va2 = reinterpret_cast<const float4*>(ap)[2];
            va3 = reinterpret_cast<const float4*>(ap)[3];
            vx0 = *reinterpret_cast<const float4*>(xp + 0 * 8 * ND);
            vx1 = *reinterpret_cast<const float4*>(xp + 1 * 8 * ND);
            vx2 = *reinterpret_cast<const float4*>(xp + 2 * 8 * ND);
            vx3 = *reinterpret_cast<const float4*>(xp + 3 * 8 * ND);
            ap += BK;
            xp += (size_t)BK * ND;
        }
        lds_barrier();   // lgkmcnt only — prefetch global loads stay in flight

        bf16x8 av[8], bv[4];
        #pragma unroll
        for (int j = 0; j < 4; ++j)
            bv[j] = *reinterpret_cast<const bf16x8*>(&Xs[(wn*64 + j*16 + lr) * LDP + lk]);
        #pragma unroll
        for (int i = 0; i < 8; ++i)
            av[i] = *reinterpret_cast<const bf16x8*>(&As[(wm*128 + i*16 + lr) * LDP + lk]);
        #pragma unroll
        for (int i = 0; i < 8; ++i)
            #pragma unroll
            for (int j = 0; j < 4; ++j)
                acc[i][j] = __builtin_amdgcn_mfma_f32_16x16x32_bf16(av[i], bv[j], acc[i][j], 0, 0, 0);
        lds_barrier();
    }

    const int ccol = lr;
    const int crow = (lane >> 4) * 4;
    #pragma unroll
    for (int i = 0; i < 8; ++i) {
        #pragma unroll
        for (int j = 0; j < 4; ++j) {
            int col = n0 + wn*64 + j*16 + ccol;
            int rw  = s0 + wm*128 + i*16 + crow;
            #pragma unroll
            for (int r = 0; r < 4; ++r)
                contexts[((size_t)b * NS + rw + r) * ND + col] = acc[i][j][r];
        }
    }
}

extern "C" void kernel_launch(void* const* d_in, const int* in_sizes, int n_in,
                              void* d_out, int out_size, void* d_ws, size_t ws_size,
                              hipStream_t stream) {
    const float* x    = (const float*)d_in[0];
    const float* W    = (const float*)d_in[1];
    const float* bias = (const float*)d_in[2];
    float* contexts = (float*)d_out;
    float* alphas   = (float*)d_out + CTX_ELEMS;
    int*   flags    = (int*)d_ws;
    // sp scratch: prefer workspace; fall back to contexts tail (overwritten only
    // after every scan block has long since read its sp row)
    float* sp = (ws_size >= (size_t)(256 + NB * NT * 4))
                    ? (float*)((char*)d_ws + 256)
                    : (float*)d_out + SP_SCRATCH_OFF;

    hipMemsetAsync(d_ws, 0, 256, stream);   // reset progress flags each call
    sp_kernel<<<dim3(NB * NT / 4), dim3(256), 0, stream>>>(x, W, bias, sp);
    fused_kernel<<<dim3(NB + 256), dim3(512), 0, stream>>>(sp, x, alphas, contexts, flags);
}

// Round 6
// 400.249 us; speedup vs baseline: 1.3906x; 1.3906x over previous
//
#include <hip/hip_runtime.h>
#include <hip/hip_bf16.h>

#define NB 32
#define NT 1024
#define ND 512
#define NS 1024

#define CTX_ELEMS (32u * 1024u * 512u)          // 16777216
#define SP_SCRATCH_OFF (CTX_ELEMS - 32u*1024u)  // stash sp in contexts tail (overwritten later)

__device__ __forceinline__ float vlog2(float x) {
    float r; asm("v_log_f32 %0, %1" : "=v"(r) : "v"(x)); return r;
}
__device__ __forceinline__ float vexp2(float x) {
    float r; asm("v_exp_f32 %0, %1" : "=v"(r) : "v"(x)); return r;
}
__device__ __forceinline__ float vrcp(float x) {
    float r; asm("v_rcp_f32 %0, %1" : "=v"(r) : "v"(x)); return r;
}

template<int ctrl, int rm, int bm, bool bc>
__device__ __forceinline__ float dppadd(float x) {
    int y = __builtin_amdgcn_update_dpp(0, __float_as_int(x), ctrl, rm, bm, bc);
    return x + __int_as_float(y);
}
// full-wave sum; valid result lands in lane 63
__device__ __forceinline__ float reduce63(float x) {
    x = dppadd<0x111, 0xf, 0xf, true >(x);   // row_shr:1
    x = dppadd<0x112, 0xf, 0xf, true >(x);   // row_shr:2
    x = dppadd<0x114, 0xf, 0xf, true >(x);   // row_shr:4
    x = dppadd<0x118, 0xf, 0xf, true >(x);   // row_shr:8
    x = dppadd<0x142, 0xa, 0xf, false>(x);   // row_bcast:15
    x = dppadd<0x143, 0xc, 0xf, false>(x);   // row_bcast:31
    return x;
}
// lane L receives x from lane L-1 (lane 0 gets 0)
__device__ __forceinline__ float wave_shr1(float x) {
    int y = __builtin_amdgcn_update_dpp(0, __float_as_int(x), 0x138, 0xf, 0xf, true);
    return __int_as_float(y);
}

// barrier that waits ONLY on LDS ops — global stores stay in flight
__device__ __forceinline__ void lds_barrier() {
    asm volatile("s_waitcnt lgkmcnt(0)" ::: "memory");
    __builtin_amdgcn_s_barrier();
    asm volatile("" ::: "memory");
}

// ---------------- kernel 1: sp[b][t] = sigmoid(dot(x[b,t,:], W) + bias) ----------------
__global__ __launch_bounds__(256) void sp_kernel(const float* __restrict__ x,
                                                 const float* __restrict__ W,
                                                 const float* __restrict__ bias,
                                                 float* __restrict__ sp)
{
    const int lane = threadIdx.x & 63;
    const int wid  = threadIdx.x >> 6;
    const int row  = blockIdx.x * 4 + wid;          // b*NT + t
    const float4* xr = reinterpret_cast<const float4*>(x + (size_t)row * ND) + lane * 2;
    const float4* wr = reinterpret_cast<const float4*>(W) + lane * 2;
    float4 xa = xr[0], xb = xr[1];
    float4 wa = wr[0], wb = wr[1];
    float d = xa.x*wa.x + xa.y*wa.y + xa.z*wa.z + xa.w*wa.w
            + xb.x*wb.x + xb.y*wb.y + xb.z*wb.z + xb.w*wb.w;
    #pragma unroll
    for (int m = 1; m < 64; m <<= 1) d += __shfl_xor(d, m);
    if (lane == 0) {
        float z = d + bias[0];
        float e = vexp2(-z * 1.442695040888963f);
        sp[row] = 1.0f / (1.0f + e);
    }
}

// ---------------- kernel 2: sequential scan, 4 waves per batch row ------
// R2-proven structure; ONLY change: in-loop __syncthreads -> lgkm-only barrier
// so the per-step global alphas stores are NOT drained on the critical chain.
__global__ __launch_bounds__(256) void scan_kernel(const float* __restrict__ sp,
                                                   float* __restrict__ alphas)
{
    const int b    = blockIdx.x;
    const int tx   = threadIdx.x;
    const int lane = tx & 63;
    const int wid  = tx >> 6;

    __shared__ float r1[2][4];   // per-wave partial sum(a)
    __shared__ float r2[2][4];   // per-wave partial sum(a*sp)
    __shared__ float rb[2][4];   // per-wave boundary value (unnormalized a at t = w*256+255)

    float spv[4], raw[4];
    {
        float4 v = *reinterpret_cast<const float4*>(sp + (size_t)b * NT + tx * 4);
        spv[0] = v.x; spv[1] = v.y; spv[2] = v.z; spv[3] = v.w;
    }
    #pragma unroll
    for (int j = 0; j < 4; ++j) raw[j] = 1e-7f;
    if (tx == 0) raw[0] = 1.0f;
    float carry = (wid == 0) ? 0.0f : 1e-7f;        // alpha value at t = w*256 - 1

    // initial u = sum(alpha0 * sp), alpha0 raw (matches reference), inv = 1
    {
        float p2 = fmaf(raw[0], spv[0], fmaf(raw[1], spv[1], fmaf(raw[2], spv[2], raw[3]*spv[3])));
        p2 = reduce63(p2);
        if (lane == 63) r2[1][wid] = p2;
    }
    lds_barrier();
    float u;
    {
        float4 v2 = *reinterpret_cast<const float4*>(r2[1]);
        u = (v2.x + v2.y) + (v2.z + v2.w);
    }
    float inv = 1.0f;

    float* outp = alphas + (size_t)b * NS * NT + tx * 4;

    for (int s = 0; s < NS; ++s) {
        const int p = s & 1;
        const float sq = 1.7f - fabsf(u - 0.5f);
        const float c1 = (1.0f - u) * inv;          // multiplies raw (unnormalized)
        const float c0 = u * inv;                   // multiplies shifted (unnormalized)

        float prev = wave_shr1(raw[3]);
        float sh0  = (lane == 0) ? carry : prev;

        float anew[4];
        {
            float v0 = fmaf(c1, raw[0], fmaf(c0, sh0,    1e-6f));
            float v1 = fmaf(c1, raw[1], fmaf(c0, raw[0], 1e-6f));
            float v2 = fmaf(c1, raw[2], fmaf(c0, raw[1], 1e-6f));
            float v3 = fmaf(c1, raw[3], fmaf(c0, raw[2], 1e-6f));
            anew[0] = vexp2(sq * vlog2(v0));
            anew[1] = vexp2(sq * vlog2(v1));
            anew[2] = vexp2(sq * vlog2(v2));
            anew[3] = vexp2(sq * vlog2(v3));
        }

        float p1 = (anew[0] + anew[1]) + (anew[2] + anew[3]);
        float p2 = fmaf(anew[0], spv[0], anew[1]*spv[1]) + fmaf(anew[2], spv[2], anew[3]*spv[3]);
        p1 = reduce63(p1);
        p2 = reduce63(p2);
        if (lane == 63) { r1[p][wid] = p1; r2[p][wid] = p2; rb[p][wid] = anew[3]; }
        lds_barrier();   // lgkm-only: alphas stores from prior steps stay in flight

        float4 v1 = *reinterpret_cast<const float4*>(r1[p]);
        float4 v2 = *reinterpret_cast<const float4*>(r2[p]);
        float bc  = rb[p][(wid == 0) ? 0 : (wid - 1)];
        carry = (wid == 0) ? 0.0f : bc;

        float t1 = (v1.x + v1.y) + (v1.z + v1.w);
        float t2 = (v2.x + v2.y) + (v2.z + v2.w);
        inv = vrcp(t1);
        u   = t2 * inv;

        float4 o;
        o.x = anew[0] * inv; o.y = anew[1] * inv; o.z = anew[2] * inv; o.w = anew[3] * inv;
        *reinterpret_cast<float4*>(outp + (size_t)s * NT) = o;

        #pragma unroll
        for (int j = 0; j < 4; ++j) raw[j] = anew[j];
    }
}

// ---------------- kernel 3: contexts[b] = alphas[b] (SxT) @ x[b] (TxD), bf16 MFMA ------
// 256x256 tile, 512 threads = 8 waves (2 x 4), each wave owns 128x64
typedef __bf16 bf16x8 __attribute__((ext_vector_type(8)));
typedef float  f32x4  __attribute__((ext_vector_type(4)));

#define BM 256
#define BN 256
#define BK 32
#define LDP 40   // padded leading dim (bf16 elems)

__global__ __launch_bounds__(512, 2) void gemm_kernel(const float* __restrict__ alphas,
                                                      const float* __restrict__ x,
                                                      float* __restrict__ contexts)
{
    __shared__ __align__(16) __bf16 As[BM * LDP];   // As[row][k]   20 KB
    __shared__ __align__(16) __bf16 Xs[BN * LDP];   // Xs[n][k]     20 KB (transposed)

    const int b  = blockIdx.z;
    const int s0 = blockIdx.y * BM;
    const int n0 = blockIdx.x * BN;
    const int tx = threadIdx.x;
    const int lane = tx & 63;
    const int wid  = tx >> 6;
    const int wm = wid >> 2;          // 0..1  (128-row slab)
    const int wn = wid & 3;           // 0..3  (64-col slab)
    const int lr = lane & 15;
    const int lk = (lane >> 4) * 8;

    f32x4 acc[8][4];
    #pragma unroll
    for (int i = 0; i < 8; ++i)
        #pragma unroll
        for (int j = 0; j < 4; ++j) acc[i][j] = (f32x4){0.f, 0.f, 0.f, 0.f};

    const int arow = tx >> 1;
    const int akb  = (tx & 1) * 16;
    const int xk0 = tx >> 6;          // 0..7
    const int xn4 = (tx & 63) * 4;    // 0..252

    const float* ap = alphas + ((size_t)b * NS + s0 + arow) * NT + akb;
    const float* xp = x + ((size_t)b * NT + xk0) * ND + n0 + xn4;

    float4 va0 = reinterpret_cast<const float4*>(ap)[0];
    float4 va1 = reinterpret_cast<const float4*>(ap)[1];
    float4 va2 = reinterpret_cast<const float4*>(ap)[2];
    float4 va3 = reinterpret_cast<const float4*>(ap)[3];
    float4 vx0 = *reinterpret_cast<const float4*>(xp + 0 * 8 * ND);
    float4 vx1 = *reinterpret_cast<const float4*>(xp + 1 * 8 * ND);
    float4 vx2 = *reinterpret_cast<const float4*>(xp + 2 * 8 * ND);
    float4 vx3 = *reinterpret_cast<const float4*>(xp + 3 * 8 * ND);
    ap += BK;
    xp += (size_t)BK * ND;

    for (int k0 = 0; k0 < NT; k0 += BK) {
        {
            bf16x8 w0, w1;
            w0[0]=(__bf16)va0.x; w0[1]=(__bf16)va0.y; w0[2]=(__bf16)va0.z; w0[3]=(__bf16)va0.w;
            w0[4]=(__bf16)va1.x; w0[5]=(__bf16)va1.y; w0[6]=(__bf16)va1.z; w0[7]=(__bf16)va1.w;
            w1[0]=(__bf16)va2.x; w1[1]=(__bf16)va2.y; w1[2]=(__bf16)va2.z; w1[3]=(__bf16)va2.w;
            w1[4]=(__bf16)va3.x; w1[5]=(__bf16)va3.y; w1[6]=(__bf16)va3.z; w1[7]=(__bf16)va3.w;
            *reinterpret_cast<bf16x8*>(&As[arow * LDP + akb])     = w0;
            *reinterpret_cast<bf16x8*>(&As[arow * LDP + akb + 8]) = w1;
            Xs[(xn4+0)*LDP + xk0]      = (__bf16)vx0.x;
            Xs[(xn4+1)*LDP + xk0]      = (__bf16)vx0.y;
            Xs[(xn4+2)*LDP + xk0]      = (__bf16)vx0.z;
            Xs[(xn4+3)*LDP + xk0]      = (__bf16)vx0.w;
            Xs[(xn4+0)*LDP + xk0 + 8]  = (__bf16)vx1.x;
            Xs[(xn4+1)*LDP + xk0 + 8]  = (__bf16)vx1.y;
            Xs[(xn4+2)*LDP + xk0 + 8]  = (__bf16)vx1.z;
            Xs[(xn4+3)*LDP + xk0 + 8]  = (__bf16)vx1.w;
            Xs[(xn4+0)*LDP + xk0 + 16] = (__bf16)vx2.x;
            Xs[(xn4+1)*LDP + xk0 + 16] = (__bf16)vx2.y;
            Xs[(xn4+2)*LDP + xk0 + 16] = (__bf16)vx2.z;
            Xs[(xn4+3)*LDP + xk0 + 16] = (__bf16)vx2.w;
            Xs[(xn4+0)*LDP + xk0 + 24] = (__bf16)vx3.x;
            Xs[(xn4+1)*LDP + xk0 + 24] = (__bf16)vx3.y;
            Xs[(xn4+2)*LDP + xk0 + 24] = (__bf16)vx3.z;
            Xs[(xn4+3)*LDP + xk0 + 24] = (__bf16)vx3.w;
        }
        if (k0 + BK < NT) {
            va0 = reinterpret_cast<const float4*>(ap)[0];
            va1 = reinterpret_cast<const float4*>(ap)[1];
            va2 = reinterpret_cast<const float4*>(ap)[2];
            va3 = reinterpret_cast<const float4*>(ap)[3];
            vx0 = *reinterpret_cast<const float4*>(xp + 0 * 8 * ND);
            vx1 = *reinterpret_cast<const float4*>(xp + 1 * 8 * ND);
            vx2 = *reinterpret_cast<const float4*>(xp + 2 * 8 * ND);
            vx3 = *reinterpret_cast<const float4*>(xp + 3 * 8 * ND);
            ap += BK;
            xp += (size_t)BK * ND;
        }
        lds_barrier();   // lgkm-only — prefetch global loads stay in flight

        bf16x8 av[8], bv[4];
        #pragma unroll
        for (int j = 0; j < 4; ++j)
            bv[j] = *reinterpret_cast<const bf16x8*>(&Xs[(wn*64 + j*16 + lr) * LDP + lk]);
        #pragma unroll
        for (int i = 0; i < 8; ++i)
            av[i] = *reinterpret_cast<const bf16x8*>(&As[(wm*128 + i*16 + lr) * LDP + lk]);
        #pragma unroll
        for (int i = 0; i < 8; ++i)
            #pragma unroll
            for (int j = 0; j < 4; ++j)
                acc[i][j] = __builtin_amdgcn_mfma_f32_16x16x32_bf16(av[i], bv[j], acc[i][j], 0, 0, 0);
        lds_barrier();
    }

    const int ccol = lr;
    const int crow = (lane >> 4) * 4;
    #pragma unroll
    for (int i = 0; i < 8; ++i) {
        #pragma unroll
        for (int j = 0; j < 4; ++j) {
            int col = n0 + wn*64 + j*16 + ccol;
            int rw  = s0 + wm*128 + i*16 + crow;
            #pragma unroll
            for (int r = 0; r < 4; ++r)
                contexts[((size_t)b * NS + rw + r) * ND + col] = acc[i][j][r];
        }
    }
}

extern "C" void kernel_launch(void* const* d_in, const int* in_sizes, int n_in,
                              void* d_out, int out_size, void* d_ws, size_t ws_size,
                              hipStream_t stream) {
    const float* x    = (const float*)d_in[0];
    const float* W    = (const float*)d_in[1];
    const float* bias = (const float*)d_in[2];
    float* contexts = (float*)d_out;
    float* alphas   = (float*)d_out + CTX_ELEMS;
    float* sp       = (float*)d_out + SP_SCRATCH_OFF;

    sp_kernel<<<dim3(NB * NT / 4), dim3(256), 0, stream>>>(x, W, bias, sp);
    scan_kernel<<<dim3(NB), dim3(256), 0, stream>>>(sp, alphas);
    gemm_kernel<<<dim3(ND / BN, NS / BM, NB), dim3(512), 0, stream>>>(alphas, x, contexts);
}